// Round 3
// baseline (167.818 us; speedup 1.0000x reference)
//
#include <hip/hip_runtime.h>
#include <math.h>

#define HF 37
#define WF 50
#define CC 512
#define POOLD 7
#define SAMPD 14

typedef float nfloat2 __attribute__((ext_vector_type(2)));

__device__ __forceinline__ float2 lerp2(float2 a, float2 b, float t) {
    float2 r; r.x = a.x + t * (b.x - a.x); r.y = a.y + t * (b.y - a.y); return r;
}
__device__ __forceinline__ float2 max2(float2 a, float2 b) {
    float2 r; r.x = fmaxf(a.x, b.x); r.y = fmaxf(a.y, b.y); return r;
}
__device__ __forceinline__ void store_nt2(float* p, float2 v) {
    nfloat2 nv; nv.x = v.x; nv.y = v.y;
    __builtin_nontemporal_store(nv, (nfloat2*)p);
}

// One block per (roi, channel-half). 128 threads * float2 = 256 channels.
// Column sweep over the ROI's x-span; per column, ONE monotone rolling row
// pass computes all 14 vertical lerps H[i] (full per-ROI row dedup: each
// (row,col) cell is loaded exactly once per block). Then the x-walk consumes
// samples for ALL 7 pooled rows from (Hp, Hc). All control flow is
// block-uniform scalar; all arrays are indexed with compile-time constants.
__global__ __launch_bounds__(128, 3) void roipool_kernel(
    const float* __restrict__ feat,    // [HF, WF, CC]
    const float* __restrict__ rois,    // [N, 4] (x1,y1,x2,y2)
    const int*   __restrict__ im_size, // [2] (h, w)
    float*       __restrict__ out,     // [N, 7, 7, CC]
    int N)
{
    int bid   = blockIdx.x;
    int n     = bid >> 1;
    int chalf = bid & 1;
    if (n >= N) return;

    const int choff = chalf * (CC / 2) + (int)threadIdx.x * 2;

    float h = (float)im_size[0];
    float w = (float)im_size[1];
    float4 box = *(const float4*)(rois + 4 * n);
    float ny1 = box.y / h, nx1 = box.x / w;
    float ny2 = box.w / h, nx2 = box.z / w;
    float dy = ny2 - ny1, dx = nx2 - nx1;
    const float inv = 1.0f / (float)(SAMPD - 1);

    // ---- y-sample schedule: trigger rows y1s[i], effective weights wye[i].
    // H[i] = lerp(row[y1s[i]-1], row[y1s[i]], wye[i]); the clamp case
    // (y1==y0, only at the bottom edge, wy==0) is folded in via wye=1.0.
    int   y1s[SAMPD];
    float wye[SAMPD];
    int rmin = 0, rmax = 0;
    #pragma unroll
    for (int i = 0; i < SAMPD; ++i) {
        float t   = (float)i * inv;
        float ys  = fmaf(dy, t, ny1) * (float)(HF - 1);
        ys        = fminf(fmaxf(ys, 0.0f), (float)(HF - 1));
        float y0f = floorf(ys);
        int   y0  = __builtin_amdgcn_readfirstlane((int)y0f);
        int   y1  = min(y0 + 1, HF - 1);
        wye[i] = (y1 == y0) ? 1.0f : (ys - y0f);
        y1s[i] = y1;
        if (i == 0)         rmin = y0;
        if (i == SAMPD - 1) rmax = y1;
    }

    // ---- x-walk bounds: pc(j) monotone; column sweep covers [cfirst, clast].
    auto sampx = [&](int j, int& pc, float& wxe) {
        float tx  = (float)j * inv;
        float xs  = fmaf(dx, tx, nx1) * (float)(WF - 1);
        xs        = fminf(fmaxf(xs, 0.0f), (float)(WF - 1));
        float x0f = floorf(xs);
        int   ci  = __builtin_amdgcn_readfirstlane((int)x0f);
        float wx  = xs - x0f;
        if (ci >= WF - 1) { pc = WF - 1; wxe = 1.0f; }
        else              { pc = ci + 1; wxe = wx; }
    };
    int pc0, pcl; float wdum;
    sampx(0, pc0, wdum);
    sampx(SAMPD - 1, pcl, wdum);
    int cfirst = pc0 - 1;
    int clast  = pcl;

    float2 Hp[SAMPD], Hc[SAMPD];
    float2 m[POOLD];
    #pragma unroll
    for (int p = 0; p < POOLD; ++p) m[p] = make_float2(-INFINITY, -INFINITY);

    const float* fbase = feat + choff;
    float*       obase = out + (size_t)n * (POOLD * POOLD) * CC + choff;

    int j = 0;  // x-sample pointer (block-uniform scalar)
    for (int c = cfirst; ; ++c) {
        // ---- row pass for column c: rolling prv/cur/nxt over rows rmin..rmax
        {
            const float* colp = fbase + (size_t)c * CC;
            int rcur = rmin;
            float2 prv, cur, nxt;
            cur = *(const float2*)(colp + (size_t)rmin * (WF * CC));
            nxt = (rmin + 1 <= rmax)
                      ? *(const float2*)(colp + (size_t)(rmin + 1) * (WF * CC))
                      : cur;
            prv = cur;
            #pragma unroll
            for (int i = 0; i < SAMPD; ++i) {
                while (rcur < y1s[i]) {          // uniform scalar advance
                    prv = cur; cur = nxt; ++rcur;
                    if (rcur + 1 <= rmax)
                        nxt = *(const float2*)(colp + (size_t)(rcur + 1) * (WF * CC));
                }
                Hc[i] = lerp2(prv, cur, wye[i]);
            }
        }
        // ---- consume all x-samples whose processing column is c
        if (c > cfirst) {
            for (;;) {
                if (j >= SAMPD) break;
                int pc; float wxe;
                sampx(j, pc, wxe);
                if (pc > c) break;
                #pragma unroll
                for (int p = 0; p < POOLD; ++p) {
                    float2 v = max2(lerp2(Hp[2 * p],     Hc[2 * p],     wxe),
                                    lerp2(Hp[2 * p + 1], Hc[2 * p + 1], wxe));
                    m[p] = max2(m[p], v);
                }
                if (j & 1) {
                    int px = j >> 1;
                    #pragma unroll
                    for (int p = 0; p < POOLD; ++p) {
                        store_nt2(obase + (size_t)(p * POOLD + px) * CC, m[p]);
                        m[p] = make_float2(-INFINITY, -INFINITY);
                    }
                }
                ++j;
            }
        }
        if (c == clast) break;
        #pragma unroll
        for (int i = 0; i < SAMPD; ++i) Hp[i] = Hc[i];
    }
}

extern "C" void kernel_launch(void* const* d_in, const int* in_sizes, int n_in,
                              void* d_out, int out_size, void* d_ws, size_t ws_size,
                              hipStream_t stream) {
    const float* feat    = (const float*)d_in[0];   // [1,37,50,512]
    const float* rois    = (const float*)d_in[1];   // [N,4]
    const int*   im_size = (const int*)d_in[2];     // [2]
    float* out = (float*)d_out;

    int N = in_sizes[1] / 4;
    int nblocks = 2 * N;   // (roi, channel-half)
    roipool_kernel<<<nblocks, 128, 0, stream>>>(feat, rois, im_size, out, N);
}

// Round 4
// 130.736 us; speedup vs baseline: 1.2836x; 1.2836x over previous
//
#include <hip/hip_runtime.h>
#include <math.h>

#define HF 37
#define WF 50
#define CC 512
#define POOLD 7
#define SAMPD 14

// Channel slicing: 4 slices of 128 channels. Slice index is the FASTEST
// grid dimension, so with the default round-robin workgroup->XCD mapping
// (XCD = bid % 8) each XCD only ever touches one 128-channel slice:
// 37*50*128*4B = 0.95 MB -- fits the 4 MB per-XCD L2 with 4x headroom
// (vs the full 7.6 MB map, which thrashes L2 and falls back to L3).
#define NSL 4
#define SLICE (CC / NSL)   // 128 channels; 64 lanes * float2

typedef float nfloat2 __attribute__((ext_vector_type(2)));

__device__ __forceinline__ float2 lerp2(float2 a, float2 b, float t) {
    float2 r; r.x = a.x + t * (b.x - a.x); r.y = a.y + t * (b.y - a.y); return r;
}
__device__ __forceinline__ float2 max2(float2 a, float2 b) {
    float2 r; r.x = fmaxf(a.x, b.x); r.y = fmaxf(a.y, b.y); return r;
}
__device__ __forceinline__ void store_nt2(float* p, float2 v) {
    nfloat2 nv; nv.x = v.x; nv.y = v.y;
    __builtin_nontemporal_store(nv, (nfloat2*)p);
}

// Load one feature column and vertically reduce to the two sample rows.
// RC (fixed per block): 0 -> both samples use the same row pair (2 loads);
// 1 -> middle row shared (3 loads); 2 -> general (4 loads).
template <int RC>
__device__ __forceinline__ void loadcol(const float* __restrict__ pbase, int col,
                                        int ro0, int ro1, int ro2, int ro3,
                                        float wya, float wyb,
                                        float2& va, float2& vb) {
    const float* p = pbase + (size_t)col * CC;
    if (RC == 0) {
        float2 rA = *(const float2*)(p + ro0);
        float2 rB = *(const float2*)(p + ro1);
        va = lerp2(rA, rB, wya);
        vb = lerp2(rA, rB, wyb);
    } else if (RC == 1) {
        float2 rA = *(const float2*)(p + ro0);
        float2 rB = *(const float2*)(p + ro1);
        float2 rC = *(const float2*)(p + ro3);
        va = lerp2(rA, rB, wya);
        vb = lerp2(rB, rC, wyb);
    } else {
        float2 r0 = *(const float2*)(p + ro0);
        float2 r1 = *(const float2*)(p + ro1);
        float2 r2 = *(const float2*)(p + ro2);
        float2 r3 = *(const float2*)(p + ro3);
        va = lerp2(r0, r1, wya);
        vb = lerp2(r2, r3, wyb);
    }
}

template <int RC>
__device__ __forceinline__ void run_row(const float* __restrict__ pbase,
                                        float* __restrict__ obase,
                                        float nx1, float nx2,
                                        int ro0, int ro1, int ro2, int ro3,
                                        float wya, float wyb) {
    const float inv = 1.0f / (float)(SAMPD - 1);

    int pcol = -1000, ccol = -1000;
    float2 vap, vbp, vac, vbc;
    float2 m0 = make_float2(-INFINITY, -INFINITY);

    // ROLLED loop: keeps live state ~1 iteration -> low VGPR -> high occupancy.
    #pragma unroll 1
    for (int sx = 0; sx < SAMPD; ++sx) {
        float tx = (float)sx * inv;
        float xs = (nx1 + (nx2 - nx1) * tx) * (float)(WF - 1);
        xs = fminf(fmaxf(xs, 0.0f), (float)(WF - 1));
        float x0f = floorf(xs);
        float wx = xs - x0f;
        int c0 = __builtin_amdgcn_readfirstlane((int)x0f);
        int c1 = min(c0 + 1, WF - 1);

        if (c0 == ccol) {
            pcol = ccol; vap = vac; vbp = vbc;
            loadcol<RC>(pbase, c1, ro0, ro1, ro2, ro3, wya, wyb, vac, vbc);
            ccol = c1;
        } else if (c0 != pcol) {
            loadcol<RC>(pbase, c0, ro0, ro1, ro2, ro3, wya, wyb, vap, vbp);
            pcol = c0;
            loadcol<RC>(pbase, c1, ro0, ro1, ro2, ro3, wya, wyb, vac, vbc);
            ccol = c1;
        }

        float2 sa = lerp2(vap, vac, wx);
        float2 sb = lerp2(vbp, vbc, wx);
        float2 mm = max2(sa, sb);
        m0 = max2(m0, mm);

        if (sx & 1) {
            store_nt2(obase + (size_t)(sx >> 1) * CC, m0);
            m0 = make_float2(-INFINITY, -INFINITY);
        }
    }
}

// One block per (roi, pooled_row, channel_slice). 64 threads * float2 = 128 ch.
__global__ __launch_bounds__(64, 8) void roipool_kernel(
    const float* __restrict__ feat,    // [HF, WF, CC]
    const float* __restrict__ rois,    // [N, 4] (x1,y1,x2,y2)
    const int*   __restrict__ im_size, // [2] (h, w)
    float*       __restrict__ out,     // [N, 7, 7, CC]
    int N)
{
    int bid = blockIdx.x;
    int cs  = bid & (NSL - 1);         // fastest dim -> pinned to XCD % NSL
    int rp  = bid >> 2;                // (roi * POOLD + py)
    int n   = rp / POOLD;
    int py  = rp - n * POOLD;
    if (n >= N) return;

    float h = (float)im_size[0];
    float w = (float)im_size[1];
    float4 box = *(const float4*)(rois + 4 * n);
    float ny1 = box.y / h, nx1 = box.x / w;
    float ny2 = box.w / h, nx2 = box.z / w;

    const float inv = 1.0f / (float)(SAMPD - 1);

    // vertical taps for the two sample rows of this pooled row (block-uniform)
    float tya = (float)(2 * py) * inv;
    float tyb = (float)(2 * py + 1) * inv;
    float ysa = (ny1 + (ny2 - ny1) * tya) * (float)(HF - 1);
    float ysb = (ny1 + (ny2 - ny1) * tyb) * (float)(HF - 1);
    ysa = fminf(fmaxf(ysa, 0.0f), (float)(HF - 1));
    ysb = fminf(fmaxf(ysb, 0.0f), (float)(HF - 1));
    float y0fa = floorf(ysa);
    float y0fb = floorf(ysb);
    float wya = ysa - y0fa;
    float wyb = ysb - y0fb;
    int iya = __builtin_amdgcn_readfirstlane((int)y0fa);
    int iyb = __builtin_amdgcn_readfirstlane((int)y0fb);
    int iya1 = min(iya + 1, HF - 1);
    int iyb1 = min(iyb + 1, HF - 1);
    int ro0 = iya  * (WF * CC);
    int ro1 = iya1 * (WF * CC);
    int ro2 = iyb  * (WF * CC);
    int ro3 = iyb1 * (WF * CC);

    const int choff = cs * SLICE + (int)threadIdx.x * 2;
    const float* pbase = feat + choff;
    float* obase = out + ((size_t)(n * POOLD + py) * POOLD) * CC + choff;

    // Row-sharing case is fixed for the whole block -> one scalar dispatch.
    if (ro2 == ro0) {
        run_row<0>(pbase, obase, nx1, nx2, ro0, ro1, ro2, ro3, wya, wyb);
    } else if (ro2 == ro1) {
        run_row<1>(pbase, obase, nx1, nx2, ro0, ro1, ro2, ro3, wya, wyb);
    } else {
        run_row<2>(pbase, obase, nx1, nx2, ro0, ro1, ro2, ro3, wya, wyb);
    }
}

extern "C" void kernel_launch(void* const* d_in, const int* in_sizes, int n_in,
                              void* d_out, int out_size, void* d_ws, size_t ws_size,
                              hipStream_t stream) {
    const float* feat    = (const float*)d_in[0];   // [1,37,50,512]
    const float* rois    = (const float*)d_in[1];   // [N,4]
    const int*   im_size = (const int*)d_in[2];     // [2]
    float* out = (float*)d_out;

    int N = in_sizes[1] / 4;
    int nblocks = N * POOLD * NSL;
    roipool_kernel<<<nblocks, 64, 0, stream>>>(feat, rois, im_size, out, N);
}